// Round 1
// baseline (100.273 us; speedup 1.0000x reference)
//
#include <hip/hip_runtime.h>
#include <hip/hip_bf16.h>

#define DIM 768
#define EPSF 1e-6f

typedef __attribute__((ext_vector_type(4))) float f32x4;
typedef __attribute__((ext_vector_type(8))) short short8;

// ---------------- ws layout ----------------
// [0)              int cnt[2]           (zeroed via hipMemsetAsync each call)
// [16)             int   idxA[4096]
// [16+16384)       int   idxB[4096]
// [16+32768)       float d2A[4096]     ||e_i + eps||^2 for A rows
// [16+49152)       float s2B[4096]     ||e_j||^2       for B rows
// [16+65536)       float partials[4096]
// total 81936 bytes

__device__ __forceinline__ short f2bf(float f) {
    return __builtin_bit_cast(short, __float2bfloat16(f));
}

template <bool ADD_EPS>
__device__ __forceinline__ short8 load_frag(const float* __restrict__ p) {
    const float4 u = *reinterpret_cast<const float4*>(p);
    const float4 v = *reinterpret_cast<const float4*>(p + 4);
    short8 f;
    if constexpr (ADD_EPS) {
        f[0] = f2bf(u.x + EPSF); f[1] = f2bf(u.y + EPSF);
        f[2] = f2bf(u.z + EPSF); f[3] = f2bf(u.w + EPSF);
        f[4] = f2bf(v.x + EPSF); f[5] = f2bf(v.y + EPSF);
        f[6] = f2bf(v.z + EPSF); f[7] = f2bf(v.w + EPSF);
    } else {
        f[0] = f2bf(u.x); f[1] = f2bf(u.y); f[2] = f2bf(u.z); f[3] = f2bf(u.w);
        f[4] = f2bf(v.x); f[5] = f2bf(v.y); f[6] = f2bf(v.z); f[7] = f2bf(v.w);
    }
    return f;
}

__device__ __forceinline__ float hinge_from_d2(float dist2) {
    float dist = sqrtf(fmaxf(dist2, 1e-12f));
    return fmaxf(1.0f - dist, 0.0f);
}

// One wave per row. Rows not in either class are skipped (no norm compute).
__global__ void k_compact(const float* __restrict__ emb,
                          const int* __restrict__ labels,
                          const int* __restrict__ depi,
                          const int* __restrict__ suii,
                          int* __restrict__ cnt,
                          int* __restrict__ idxA, int* __restrict__ idxB,
                          float* __restrict__ d2A, float* __restrict__ s2B,
                          int nrows)
{
    const int row  = blockIdx.x * 4 + (threadIdx.x >> 6);
    const int lane = threadIdx.x & 63;
    if (row >= nrows) return;
    const int lab = labels[row];
    const int dep = depi[0], sui = suii[0];
    const bool isA = (lab == dep), isB = (lab == sui);
    if (!(isA || isB)) return;                 // wave-uniform skip

    const float* rp = emb + (size_t)row * DIM;
    float s2 = 0.f, d2 = 0.f;
    #pragma unroll
    for (int c = 0; c < 3; ++c) {
        float4 v = *reinterpret_cast<const float4*>(rp + c * 256 + lane * 4);
        s2 += v.x * v.x + v.y * v.y + v.z * v.z + v.w * v.w;
        float dx = v.x + EPSF, dy = v.y + EPSF, dz = v.z + EPSF, dw = v.w + EPSF;
        d2 += dx * dx + dy * dy + dz * dz + dw * dw;
    }
    #pragma unroll
    for (int off = 32; off; off >>= 1) {
        s2 += __shfl_down(s2, off);
        d2 += __shfl_down(d2, off);
    }
    if (lane == 0) {
        if (isA) { int p = atomicAdd(&cnt[0], 1); idxA[p] = row; d2A[p] = d2; }
        if (isB) { int p = atomicAdd(&cnt[1], 1); idxB[p] = row; s2B[p] = s2; }
    }
}

// Block = 64x64 pairs; 4 waves, each owns a 32x32 sub-tile (2x2 MFMA 16x16x32).
// Fragments loaded global->reg (active set is L2/L3 resident), converted to bf16.
__global__ void k_pairs(const float* __restrict__ emb,
                        const int* __restrict__ cnt,
                        const int* __restrict__ idxA, const int* __restrict__ idxB,
                        const float* __restrict__ d2A, const float* __restrict__ s2B,
                        float* __restrict__ partials)
{
    const int nA = cnt[0], nB = cnt[1];
    const int bi = blockIdx.y, bj = blockIdx.x;
    const int bid = bi * gridDim.x + bj;
    const int tid = threadIdx.x;
    if ((bi << 6) >= nA || (bj << 6) >= nB) {
        if (tid == 0) partials[bid] = 0.f;     // every block writes its slot
        return;
    }
    const int wid = tid >> 6, lane = tid & 63;
    const int a0 = (bi << 6) + ((wid >> 1) << 5);   // wave's A base (32 rows)
    const int b0 = (bj << 6) + ((wid & 1) << 5);    // wave's B base (32 rows)
    const int r  = lane & 15;                        // frag row within 16
    const int kq = lane >> 4;                        // k-chunk (8 elems each)

    const int ga0 = a0 + r, ga1 = a0 + 16 + r;
    const int gb0 = b0 + r, gb1 = b0 + 16 + r;
    const float* pa0 = emb + (size_t)idxA[ga0 < nA ? ga0 : 0] * DIM + kq * 8;
    const float* pa1 = emb + (size_t)idxA[ga1 < nA ? ga1 : 0] * DIM + kq * 8;
    const float* pb0 = emb + (size_t)idxB[gb0 < nB ? gb0 : 0] * DIM + kq * 8;
    const float* pb1 = emb + (size_t)idxB[gb1 < nB ? gb1 : 0] * DIM + kq * 8;

    f32x4 acc00 = {0.f, 0.f, 0.f, 0.f};
    f32x4 acc01 = {0.f, 0.f, 0.f, 0.f};
    f32x4 acc10 = {0.f, 0.f, 0.f, 0.f};
    f32x4 acc11 = {0.f, 0.f, 0.f, 0.f};

    for (int k0 = 0; k0 < DIM; k0 += 32) {
        short8 fa0 = load_frag<true >(pa0 + k0);   // d-side gets +eps
        short8 fa1 = load_frag<true >(pa1 + k0);
        short8 fb0 = load_frag<false>(pb0 + k0);
        short8 fb1 = load_frag<false>(pb1 + k0);
        acc00 = __builtin_amdgcn_mfma_f32_16x16x32_bf16(fa0, fb0, acc00, 0, 0, 0);
        acc01 = __builtin_amdgcn_mfma_f32_16x16x32_bf16(fa0, fb1, acc01, 0, 0, 0);
        acc10 = __builtin_amdgcn_mfma_f32_16x16x32_bf16(fa1, fb0, acc10, 0, 0, 0);
        acc11 = __builtin_amdgcn_mfma_f32_16x16x32_bf16(fa1, fb1, acc11, 0, 0, 0);
    }

    // C/D mapping (m89-verified): col = lane&15, row = (lane>>4)*4 + reg
    float hsum = 0.f;
    const int mA0 = a0 + (kq << 2);
    const int mA1 = mA0 + 16;
    const int nB0 = b0 + r;
    const int nB1 = nB0 + 16;
    const float s20 = (nB0 < nB) ? s2B[nB0] : 0.f;
    const float s21 = (nB1 < nB) ? s2B[nB1] : 0.f;
    #pragma unroll
    for (int j = 0; j < 4; ++j) {
        const int aLo = mA0 + j, aHi = mA1 + j;
        const float d2lo = (aLo < nA) ? d2A[aLo] : 0.f;
        const float d2hi = (aHi < nA) ? d2A[aHi] : 0.f;
        if (aLo < nA && nB0 < nB) hsum += hinge_from_d2(d2lo + s20 - 2.f * acc00[j]);
        if (aLo < nA && nB1 < nB) hsum += hinge_from_d2(d2lo + s21 - 2.f * acc01[j]);
        if (aHi < nA && nB0 < nB) hsum += hinge_from_d2(d2hi + s20 - 2.f * acc10[j]);
        if (aHi < nA && nB1 < nB) hsum += hinge_from_d2(d2hi + s21 - 2.f * acc11[j]);
    }
    #pragma unroll
    for (int off = 32; off; off >>= 1) hsum += __shfl_down(hsum, off);

    __shared__ float wsum[4];
    if (lane == 0) wsum[wid] = hsum;
    __syncthreads();
    if (tid == 0) partials[bid] = wsum[0] + wsum[1] + wsum[2] + wsum[3];
}

// Deterministic fixed-order reduction + final divide.
__global__ void k_final(const float* __restrict__ partials,
                        const int* __restrict__ cnt,
                        float* __restrict__ out, int np)
{
    __shared__ float sm[256];
    float s = 0.f;
    for (int i = threadIdx.x; i < np; i += 256) s += partials[i];
    sm[threadIdx.x] = s;
    __syncthreads();
    for (int off = 128; off; off >>= 1) {
        if (threadIdx.x < off) sm[threadIdx.x] += sm[threadIdx.x + off];
        __syncthreads();
    }
    if (threadIdx.x == 0) {
        long long c = (long long)cnt[0] * (long long)cnt[1];
        out[0] = (c > 0) ? sm[0] / (float)c : 0.f;
    }
}

extern "C" void kernel_launch(void* const* d_in, const int* in_sizes, int n_in,
                              void* d_out, int out_size, void* d_ws, size_t ws_size,
                              hipStream_t stream)
{
    const float* emb   = (const float*)d_in[0];
    const int* labels  = (const int*)d_in[1];
    const int* depi    = (const int*)d_in[2];
    const int* suii    = (const int*)d_in[3];
    float* out         = (float*)d_out;

    char* ws = (char*)d_ws;
    int*   cnt      = (int*)ws;
    int*   idxA     = (int*)(ws + 16);
    int*   idxB     = (int*)(ws + 16 + 16384);
    float* d2A      = (float*)(ws + 16 + 32768);
    float* s2B      = (float*)(ws + 16 + 49152);
    float* partials = (float*)(ws + 16 + 65536);

    const int nrows = in_sizes[0] / DIM;   // 4096

    hipMemsetAsync(cnt, 0, 2 * sizeof(int), stream);
    k_compact<<<(nrows + 3) / 4, 256, 0, stream>>>(emb, labels, depi, suii,
                                                   cnt, idxA, idxB, d2A, s2B, nrows);
    dim3 grid((nrows + 63) / 64, (nrows + 63) / 64);
    k_pairs<<<grid, 256, 0, stream>>>(emb, cnt, idxA, idxB, d2A, s2B, partials);
    k_final<<<1, 256, 0, stream>>>(partials, cnt, out, grid.x * grid.y);
}

// Round 4
// 55.502 us; speedup vs baseline: 1.8067x; 1.8067x over previous
//
#include <hip/hip_runtime.h>
#include <hip/hip_bf16.h>

#define DIM   768
#define KITER (DIM / 32)          // 24 MFMA k-steps per 16x16 tile
#define EPSF  1e-6f
#define MAXB  4096
#define NPB   512                 // persistent pairs blocks (4 waves each)

typedef __attribute__((ext_vector_type(4))) float f32x4;
typedef __attribute__((ext_vector_type(8))) short short8;
typedef __attribute__((ext_vector_type(4))) unsigned short ushort4_t;

// ---------------- ws layout ----------------
// [0)      int cnt[2]; int done;             (first 16 B zeroed via memsetAsync)
// [64)     float d2A[4096]                   ||e+eps||^2, compacted A order
// [64+16K) float s2B[4096]                   ||e||^2,     compacted B order
// [64+32K) float partials[NPB]  (4K reserved)
// [36928)  COMP path:   ushort Abf[4096*768], ushort Bbf[4096*768]  (12.6 MB)
//          fallback:    int idxA[4096], int idxB[4096]
#define OFF_D2A   64
#define OFF_S2B   (64 + 16384)
#define OFF_PART  (64 + 32768)
#define OFF_VAR   (64 + 32768 + 4096)
#define NEED_COMP ((size_t)OFF_VAR + 2ull * MAXB * DIM * 2ull)

__device__ __forceinline__ unsigned short f2bf(float f) {
    return __builtin_bit_cast(unsigned short, __float2bfloat16(f));
}

__device__ __forceinline__ float hinge_from_d2(float dist2) {
    float dist = sqrtf(fmaxf(dist2, 1e-12f));
    return fmaxf(1.0f - dist, 0.0f);
}

template <bool ADD_EPS>
__device__ __forceinline__ short8 load_frag(const float* __restrict__ p) {
    const float4 u = *reinterpret_cast<const float4*>(p);
    const float4 v = *reinterpret_cast<const float4*>(p + 4);
    short8 f;
    if constexpr (ADD_EPS) {
        f[0] = (short)f2bf(u.x + EPSF); f[1] = (short)f2bf(u.y + EPSF);
        f[2] = (short)f2bf(u.z + EPSF); f[3] = (short)f2bf(u.w + EPSF);
        f[4] = (short)f2bf(v.x + EPSF); f[5] = (short)f2bf(v.y + EPSF);
        f[6] = (short)f2bf(v.z + EPSF); f[7] = (short)f2bf(v.w + EPSF);
    } else {
        f[0] = (short)f2bf(u.x); f[1] = (short)f2bf(u.y);
        f[2] = (short)f2bf(u.z); f[3] = (short)f2bf(u.w);
        f[4] = (short)f2bf(v.x); f[5] = (short)f2bf(v.y);
        f[6] = (short)f2bf(v.z); f[7] = (short)f2bf(v.w);
    }
    return f;
}

// One wave per row. Computes fp32 norms; COMP path also writes the row,
// converted to bf16 (A side with +eps pre-applied), to a compacted buffer.
template <bool COMP>
__global__ void k_compact(const float* __restrict__ emb,
                          const int* __restrict__ labels,
                          const int* __restrict__ depi,
                          const int* __restrict__ suii,
                          int* __restrict__ cnt,
                          float* __restrict__ d2A, float* __restrict__ s2B,
                          int* __restrict__ idxA, int* __restrict__ idxB,
                          unsigned short* __restrict__ Abf,
                          unsigned short* __restrict__ Bbf,
                          int nrows)
{
    const int row  = blockIdx.x * 4 + (threadIdx.x >> 6);
    const int lane = threadIdx.x & 63;
    if (row >= nrows) return;
    const int lab = labels[row];
    const bool isA = (lab == depi[0]);
    const bool isB = (lab == suii[0]);
    if (!(isA | isB)) return;                      // wave-uniform skip

    const float* rp = emb + (size_t)row * DIM;
    float4 v[3];
    float s2 = 0.f, d2 = 0.f;
    #pragma unroll
    for (int c = 0; c < 3; ++c) {
        v[c] = *reinterpret_cast<const float4*>(rp + c * 256 + lane * 4);
        s2 += v[c].x * v[c].x + v[c].y * v[c].y + v[c].z * v[c].z + v[c].w * v[c].w;
        float dx = v[c].x + EPSF, dy = v[c].y + EPSF;
        float dz = v[c].z + EPSF, dw = v[c].w + EPSF;
        d2 += dx * dx + dy * dy + dz * dz + dw * dw;
    }
    #pragma unroll
    for (int off = 32; off; off >>= 1) {
        s2 += __shfl_xor(s2, off);
        d2 += __shfl_xor(d2, off);
    }
    if (isA) {
        int p = 0;
        if (lane == 0) {
            p = atomicAdd(&cnt[0], 1);
            d2A[p] = d2;
            if (!COMP) idxA[p] = row;
        }
        if (COMP) {
            p = __shfl(p, 0);
            unsigned short* dst = Abf + (size_t)p * DIM;
            #pragma unroll
            for (int c = 0; c < 3; ++c) {
                ushort4_t w;
                w[0] = f2bf(v[c].x + EPSF); w[1] = f2bf(v[c].y + EPSF);
                w[2] = f2bf(v[c].z + EPSF); w[3] = f2bf(v[c].w + EPSF);
                *reinterpret_cast<ushort4_t*>(dst + c * 256 + lane * 4) = w;
            }
        }
    }
    if (isB) {
        int p = 0;
        if (lane == 0) {
            p = atomicAdd(&cnt[1], 1);
            s2B[p] = s2;
            if (!COMP) idxB[p] = row;
        }
        if (COMP) {
            p = __shfl(p, 0);
            unsigned short* dst = Bbf + (size_t)p * DIM;
            #pragma unroll
            for (int c = 0; c < 3; ++c) {
                ushort4_t w;
                w[0] = f2bf(v[c].x); w[1] = f2bf(v[c].y);
                w[2] = f2bf(v[c].z); w[3] = f2bf(v[c].w);
                *reinterpret_cast<ushort4_t*>(dst + c * 256 + lane * 4) = w;
            }
        }
    }
}

// Persistent grid: each wave grid-strides over 16x16 pair tiles (one MFMA
// chain per tile). Final reduction fused via device-scope done-counter.
template <bool COMP>
__global__ void __launch_bounds__(256)
k_pairs(const float* __restrict__ emb,
        const int* __restrict__ cnt,
        const float* __restrict__ d2A, const float* __restrict__ s2B,
        const int* __restrict__ idxA, const int* __restrict__ idxB,
        const unsigned short* __restrict__ Abf,
        const unsigned short* __restrict__ Bbf,
        float* __restrict__ partials,
        int* __restrict__ done,
        float* __restrict__ out)
{
    __shared__ float wsum[4];
    __shared__ float sm[256];
    __shared__ int   slast;

    const int nA = cnt[0], nB = cnt[1];
    const unsigned nTi = (unsigned)(nA + 15) >> 4;
    const unsigned nTj = (unsigned)(nB + 15) >> 4;
    const unsigned T   = nTi * nTj;
    const int tid  = threadIdx.x;
    const int wid  = tid >> 6, lane = tid & 63;
    const int r    = lane & 15, kq = lane >> 4;
    const unsigned nw = gridDim.x * 4;
    float wacc = 0.f;

    for (unsigned t = blockIdx.x * 4 + wid; t < T; t += nw) {
        const unsigned ti = t / nTj;
        const unsigned tj = t - ti * nTj;
        const int a0 = (int)(ti << 4), b0 = (int)(tj << 4);
        const int ar = min(a0 + r, nA - 1);       // clamp; epilogue masks
        const int br = min(b0 + r, nB - 1);
        f32x4 acc = {0.f, 0.f, 0.f, 0.f};
        if constexpr (COMP) {
            const short8* pa = reinterpret_cast<const short8*>(Abf + (size_t)ar * DIM) + kq;
            const short8* pb = reinterpret_cast<const short8*>(Bbf + (size_t)br * DIM) + kq;
            #pragma unroll 8
            for (int kk = 0; kk < KITER; ++kk)
                acc = __builtin_amdgcn_mfma_f32_16x16x32_bf16(pa[4 * kk], pb[4 * kk],
                                                              acc, 0, 0, 0);
        } else {
            const float* pa = emb + (size_t)idxA[ar] * DIM + kq * 8;
            const float* pb = emb + (size_t)idxB[br] * DIM + kq * 8;
            #pragma unroll 4
            for (int kk = 0; kk < KITER; ++kk) {
                short8 fa = load_frag<true >(pa + 32 * kk);
                short8 fb = load_frag<false>(pb + 32 * kk);
                acc = __builtin_amdgcn_mfma_f32_16x16x32_bf16(fa, fb, acc, 0, 0, 0);
            }
        }
        // C/D mapping: col = lane&15 (B index), row = (lane>>4)*4 + reg (A index)
        const int bcol = b0 + r;
        if (bcol < nB) {
            const float s2v = s2B[bcol];
            #pragma unroll
            for (int j = 0; j < 4; ++j) {
                const int arow = a0 + (kq << 2) + j;
                if (arow < nA)
                    wacc += hinge_from_d2(d2A[arow] + s2v - 2.f * acc[j]);
            }
        }
    }

    #pragma unroll
    for (int off = 32; off; off >>= 1) wacc += __shfl_down(wacc, off);
    if (lane == 0) wsum[wid] = wacc;
    __syncthreads();
    if (tid == 0) {
        float bs = wsum[0] + wsum[1] + wsum[2] + wsum[3];
        __hip_atomic_store(&partials[blockIdx.x], bs,
                           __ATOMIC_RELEASE, __HIP_MEMORY_SCOPE_AGENT);
        int old = __hip_atomic_fetch_add(done, 1,
                                         __ATOMIC_ACQ_REL, __HIP_MEMORY_SCOPE_AGENT);
        slast = (old == (int)gridDim.x - 1) ? 1 : 0;
    }
    __syncthreads();
    if (slast) {                                   // last block: final reduce
        float s = 0.f;
        for (int i = tid; i < (int)gridDim.x; i += 256)
            s += __hip_atomic_load(&partials[i],
                                   __ATOMIC_RELAXED, __HIP_MEMORY_SCOPE_AGENT);
        sm[tid] = s;
        __syncthreads();
        for (int off = 128; off; off >>= 1) {
            if (tid < off) sm[tid] += sm[tid + off];
            __syncthreads();
        }
        if (tid == 0) {
            long long c = (long long)nA * (long long)nB;
            out[0] = (c > 0) ? sm[0] / (float)c : 0.f;
        }
    }
}

extern "C" void kernel_launch(void* const* d_in, const int* in_sizes, int n_in,
                              void* d_out, int out_size, void* d_ws, size_t ws_size,
                              hipStream_t stream)
{
    const float* emb  = (const float*)d_in[0];
    const int* labels = (const int*)d_in[1];
    const int* depi   = (const int*)d_in[2];
    const int* suii   = (const int*)d_in[3];
    float* out        = (float*)d_out;

    char* ws = (char*)d_ws;
    int*   cnt      = (int*)ws;                    // cnt[0..1], done at +8
    int*   done     = (int*)(ws + 8);
    float* d2A      = (float*)(ws + OFF_D2A);
    float* s2B      = (float*)(ws + OFF_S2B);
    float* partials = (float*)(ws + OFF_PART);
    // variable region: COMP -> bf16 buffers; fallback -> index arrays
    unsigned short* Abf = (unsigned short*)(ws + OFF_VAR);
    unsigned short* Bbf = Abf + (size_t)MAXB * DIM;
    int* idxA = (int*)(ws + OFF_VAR);
    int* idxB = idxA + MAXB;

    const int nrows = in_sizes[0] / DIM;           // 4096

    hipMemsetAsync(ws, 0, 16, stream);             // cnt + done
    if (ws_size >= NEED_COMP) {
        k_compact<true><<<(nrows + 3) / 4, 256, 0, stream>>>(
            emb, labels, depi, suii, cnt, d2A, s2B, idxA, idxB, Abf, Bbf, nrows);
        k_pairs<true><<<NPB, 256, 0, stream>>>(
            emb, cnt, d2A, s2B, idxA, idxB, Abf, Bbf, partials, done, out);
    } else {
        k_compact<false><<<(nrows + 3) / 4, 256, 0, stream>>>(
            emb, labels, depi, suii, cnt, d2A, s2B, idxA, idxB, Abf, Bbf, nrows);
        k_pairs<false><<<NPB, 256, 0, stream>>>(
            emb, cnt, d2A, s2B, idxA, idxB, Abf, Bbf, partials, done, out);
    }
}

// Round 5
// 26.795 us; speedup vs baseline: 3.7423x; 2.0714x over previous
//
#include <hip/hip_runtime.h>
#include <hip/hip_bf16.h>

#define DIM   768
#define KITER (DIM / 32)          // 24 MFMA k-steps
#define EPSF  1e-6f
#define MAXB  4096
#define NPB   256                 // pairs blocks (4 waves each)

typedef __attribute__((ext_vector_type(4))) float f32x4;
typedef __attribute__((ext_vector_type(8))) short short8;
typedef __attribute__((ext_vector_type(4))) unsigned short ushort4_t;

// ---------------- ws layout ----------------
// [0)        int   cnt[2]                (written by k_classify every call)
// [64)       float d2A[4096]             ||e+eps||^2, compacted A order
// [64+16K)   float s2B[4096]             ||e||^2,     compacted B order
// [64+32K)   float partials[NPB]         (4K reserved)
// [36928)    int   idxA[4096]
// [53312)    int   idxB[4096]
// [69696)    COMP: ushort Abf[4096*768], ushort Bbf[4096*768]   (12.6 MB)
#define OFF_D2A   64
#define OFF_S2B   (64 + 16384)
#define OFF_PART  (64 + 32768)
#define OFF_IDXA  (64 + 32768 + 4096)
#define OFF_IDXB  (OFF_IDXA + 16384)
#define OFF_BF    (OFF_IDXB + 16384)
#define NEED_COMP ((size_t)OFF_BF + 2ull * MAXB * DIM * 2ull)

__device__ __forceinline__ unsigned short f2bf(float f) {
    return __builtin_bit_cast(unsigned short, __float2bfloat16(f));
}

__device__ __forceinline__ float hinge_from_d2(float dist2) {
    float dist = sqrtf(fmaxf(dist2, 1e-12f));
    return fmaxf(1.0f - dist, 0.0f);
}

template <bool ADD_EPS>
__device__ __forceinline__ short8 load_frag(const float* __restrict__ p) {
    const float4 u = *reinterpret_cast<const float4*>(p);
    const float4 v = *reinterpret_cast<const float4*>(p + 4);
    short8 f;
    if constexpr (ADD_EPS) {
        f[0] = (short)f2bf(u.x + EPSF); f[1] = (short)f2bf(u.y + EPSF);
        f[2] = (short)f2bf(u.z + EPSF); f[3] = (short)f2bf(u.w + EPSF);
        f[4] = (short)f2bf(v.x + EPSF); f[5] = (short)f2bf(v.y + EPSF);
        f[6] = (short)f2bf(v.z + EPSF); f[7] = (short)f2bf(v.w + EPSF);
    } else {
        f[0] = (short)f2bf(u.x); f[1] = (short)f2bf(u.y);
        f[2] = (short)f2bf(u.z); f[3] = (short)f2bf(u.w);
        f[4] = (short)f2bf(v.x); f[5] = (short)f2bf(v.y);
        f[6] = (short)f2bf(v.z); f[7] = (short)f2bf(v.w);
    }
    return f;
}

// ONE block, 1024 threads: deterministic compaction via packed prefix scan.
// packed int = aCount | (bCount<<16); totals <= 4096 so fields never carry.
__global__ void __launch_bounds__(1024)
k_classify(const int* __restrict__ labels,
           const int* __restrict__ depi, const int* __restrict__ suii,
           int* __restrict__ cnt,
           int* __restrict__ idxA, int* __restrict__ idxB, int nrows)
{
    __shared__ int wtot[16];
    const int tid = threadIdx.x, lane = tid & 63, wv = tid >> 6;
    const int dep = depi[0], sui = suii[0];
    int baseA = 0, baseB = 0;
    for (int chunk = 0; chunk < nrows; chunk += 4096) {
        const int r0 = chunk + tid * 4;
        int l[4];
        #pragma unroll
        for (int j = 0; j < 4; ++j)
            l[j] = (r0 + j < nrows) ? labels[r0 + j] : 0x7fffffff;
        int ac = 0, bc = 0;
        #pragma unroll
        for (int j = 0; j < 4; ++j) { ac += (l[j] == dep); bc += (l[j] == sui); }
        int incl = ac | (bc << 16);
        const int own = incl;
        #pragma unroll
        for (int off = 1; off < 64; off <<= 1) {
            int n = __shfl_up(incl, off);
            if (lane >= off) incl += n;
        }
        if (lane == 63) wtot[wv] = incl;
        __syncthreads();
        if (tid < 16) {
            int v = wtot[tid];
            #pragma unroll
            for (int off = 1; off < 16; off <<= 1) {
                int n = __shfl_up(v, off);
                if (tid >= off) v += n;
            }
            wtot[tid] = v;               // inclusive over waves
        }
        __syncthreads();
        const int wbase = wv ? wtot[wv - 1] : 0;
        const int excl  = wbase + incl - own;
        int pA = baseA + (excl & 0xFFFF);
        int pB = baseB + (excl >> 16);
        #pragma unroll
        for (int j = 0; j < 4; ++j) {
            const int row = r0 + j;
            if (row < nrows) {
                if (l[j] == dep) idxA[pA++] = row;
                if (l[j] == sui) idxB[pB++] = row;
            }
        }
        const int tot = wtot[15];
        baseA += tot & 0xFFFF;
        baseB += tot >> 16;
        __syncthreads();                 // wtot reused next chunk
    }
    if (tid == 0) { cnt[0] = baseA; cnt[1] = baseB; }
}

// Wave w handles compacted slot w: A rows first [0,nA), then B rows [0,nB).
// No atomics. COMP also writes the bf16 row (A side with +eps baked in).
template <bool COMP>
__global__ void k_norms(const float* __restrict__ emb,
                        const int* __restrict__ cnt,
                        const int* __restrict__ idxA, const int* __restrict__ idxB,
                        float* __restrict__ d2A, float* __restrict__ s2B,
                        unsigned short* __restrict__ Abf,
                        unsigned short* __restrict__ Bbf)
{
    const int w    = blockIdx.x * 4 + (threadIdx.x >> 6);
    const int lane = threadIdx.x & 63;
    const int nA = cnt[0], nB = cnt[1];
    bool isA; int p;
    if (w < nA)               { isA = true;  p = w; }
    else if (w - nA < nB)     { isA = false; p = w - nA; }
    else return;                                  // wave-uniform exit

    const int row = isA ? idxA[p] : idxB[p];
    const float* rp = emb + (size_t)row * DIM;
    float4 v[3];
    float acc = 0.f;
    #pragma unroll
    for (int c = 0; c < 3; ++c) {
        v[c] = *reinterpret_cast<const float4*>(rp + c * 256 + lane * 4);
        if (isA) { v[c].x += EPSF; v[c].y += EPSF; v[c].z += EPSF; v[c].w += EPSF; }
        acc += v[c].x * v[c].x + v[c].y * v[c].y + v[c].z * v[c].z + v[c].w * v[c].w;
    }
    #pragma unroll
    for (int off = 32; off; off >>= 1) acc += __shfl_xor(acc, off);
    if (lane == 0) { if (isA) d2A[p] = acc; else s2B[p] = acc; }
    if constexpr (COMP) {
        unsigned short* dst = (isA ? Abf : Bbf) + (size_t)p * DIM;
        #pragma unroll
        for (int c = 0; c < 3; ++c) {
            ushort4_t wd;
            wd[0] = f2bf(v[c].x); wd[1] = f2bf(v[c].y);
            wd[2] = f2bf(v[c].z); wd[3] = f2bf(v[c].w);
            *reinterpret_cast<ushort4_t*>(dst + c * 256 + lane * 4) = wd;
        }
    }
}

// Each wave owns a 32x32 pair tile = 2x2 MFMA(16x16x32) sub-tiles -> 4
// independent accumulator chains. Tiles spread as t = bid + wid*grid so all
// blocks engage. One plain partial store per block; no atomics.
template <bool COMP>
__global__ void __launch_bounds__(256)
k_pairs(const float* __restrict__ emb,
        const int* __restrict__ cnt,
        const float* __restrict__ d2A, const float* __restrict__ s2B,
        const int* __restrict__ idxA, const int* __restrict__ idxB,
        const unsigned short* __restrict__ Abf,
        const unsigned short* __restrict__ Bbf,
        float* __restrict__ partials)
{
    __shared__ float wsum[4];
    const int nA = cnt[0], nB = cnt[1];
    const unsigned nTi = (unsigned)(nA + 31) >> 5;
    const unsigned nTj = (unsigned)(nB + 31) >> 5;
    const unsigned T   = nTi * nTj;
    const int tid = threadIdx.x, wv = tid >> 6, lane = tid & 63;
    const int r = lane & 15, kq = lane >> 4;
    float wacc = 0.f;

    for (unsigned t = blockIdx.x + wv * gridDim.x; t < T; t += gridDim.x * 4) {
        const unsigned ti = t / nTj;
        const unsigned tj = t - ti * nTj;
        const int a0 = (int)(ti << 5), b0 = (int)(tj << 5);
        const int ar0 = min(a0 + r,      nA - 1);   // clamp; epilogue masks
        const int ar1 = min(a0 + 16 + r, nA - 1);
        const int br0 = min(b0 + r,      nB - 1);
        const int br1 = min(b0 + 16 + r, nB - 1);
        f32x4 acc00 = {0.f,0.f,0.f,0.f}, acc01 = {0.f,0.f,0.f,0.f};
        f32x4 acc10 = {0.f,0.f,0.f,0.f}, acc11 = {0.f,0.f,0.f,0.f};

        if constexpr (COMP) {
            const short8* pa0 = reinterpret_cast<const short8*>(Abf + (size_t)ar0 * DIM) + kq;
            const short8* pa1 = reinterpret_cast<const short8*>(Abf + (size_t)ar1 * DIM) + kq;
            const short8* pb0 = reinterpret_cast<const short8*>(Bbf + (size_t)br0 * DIM) + kq;
            const short8* pb1 = reinterpret_cast<const short8*>(Bbf + (size_t)br1 * DIM) + kq;
            #pragma unroll 6
            for (int kk = 0; kk < KITER; ++kk) {
                const short8 fa0 = pa0[4 * kk], fa1 = pa1[4 * kk];
                const short8 fb0 = pb0[4 * kk], fb1 = pb1[4 * kk];
                acc00 = __builtin_amdgcn_mfma_f32_16x16x32_bf16(fa0, fb0, acc00, 0, 0, 0);
                acc01 = __builtin_amdgcn_mfma_f32_16x16x32_bf16(fa0, fb1, acc01, 0, 0, 0);
                acc10 = __builtin_amdgcn_mfma_f32_16x16x32_bf16(fa1, fb0, acc10, 0, 0, 0);
                acc11 = __builtin_amdgcn_mfma_f32_16x16x32_bf16(fa1, fb1, acc11, 0, 0, 0);
            }
        } else {
            const float* qa0 = emb + (size_t)idxA[ar0] * DIM + kq * 8;
            const float* qa1 = emb + (size_t)idxA[ar1] * DIM + kq * 8;
            const float* qb0 = emb + (size_t)idxB[br0] * DIM + kq * 8;
            const float* qb1 = emb + (size_t)idxB[br1] * DIM + kq * 8;
            #pragma unroll 3
            for (int kk = 0; kk < KITER; ++kk) {
                const short8 fa0 = load_frag<true >(qa0 + 32 * kk);
                const short8 fa1 = load_frag<true >(qa1 + 32 * kk);
                const short8 fb0 = load_frag<false>(qb0 + 32 * kk);
                const short8 fb1 = load_frag<false>(qb1 + 32 * kk);
                acc00 = __builtin_amdgcn_mfma_f32_16x16x32_bf16(fa0, fb0, acc00, 0, 0, 0);
                acc01 = __builtin_amdgcn_mfma_f32_16x16x32_bf16(fa0, fb1, acc01, 0, 0, 0);
                acc10 = __builtin_amdgcn_mfma_f32_16x16x32_bf16(fa1, fb0, acc10, 0, 0, 0);
                acc11 = __builtin_amdgcn_mfma_f32_16x16x32_bf16(fa1, fb1, acc11, 0, 0, 0);
            }
        }

        // C/D mapping: col = lane&15 (B idx), row = (lane>>4)*4 + reg (A idx)
        const int bc0 = b0 + r, bc1 = b0 + 16 + r;
        const float s20 = (bc0 < nB) ? s2B[bc0] : 0.f;
        const float s21 = (bc1 < nB) ? s2B[bc1] : 0.f;
        #pragma unroll
        for (int j = 0; j < 4; ++j) {
            const int arl = a0 + (kq << 2) + j;
            const int arh = arl + 16;
            const float d2l = (arl < nA) ? d2A[arl] : 0.f;
            const float d2h = (arh < nA) ? d2A[arh] : 0.f;
            if (arl < nA && bc0 < nB) wacc += hinge_from_d2(d2l + s20 - 2.f * acc00[j]);
            if (arl < nA && bc1 < nB) wacc += hinge_from_d2(d2l + s21 - 2.f * acc01[j]);
            if (arh < nA && bc0 < nB) wacc += hinge_from_d2(d2h + s20 - 2.f * acc10[j]);
            if (arh < nA && bc1 < nB) wacc += hinge_from_d2(d2h + s21 - 2.f * acc11[j]);
        }
    }

    #pragma unroll
    for (int off = 32; off; off >>= 1) wacc += __shfl_down(wacc, off);
    if (lane == 0) wsum[wv] = wacc;
    __syncthreads();
    if (tid == 0)
        partials[blockIdx.x] = wsum[0] + wsum[1] + wsum[2] + wsum[3];
}

// Tiny deterministic tree reduce of NPB partials + final divide.
__global__ void __launch_bounds__(NPB)
k_final(const float* __restrict__ partials, const int* __restrict__ cnt,
        float* __restrict__ out)
{
    __shared__ float sm[NPB];
    const int tid = threadIdx.x;
    sm[tid] = partials[tid];
    __syncthreads();
    for (int off = NPB / 2; off; off >>= 1) {
        if (tid < off) sm[tid] += sm[tid + off];
        __syncthreads();
    }
    if (tid == 0) {
        const long long c = (long long)cnt[0] * (long long)cnt[1];
        out[0] = (c > 0) ? sm[0] / (float)c : 0.f;
    }
}

extern "C" void kernel_launch(void* const* d_in, const int* in_sizes, int n_in,
                              void* d_out, int out_size, void* d_ws, size_t ws_size,
                              hipStream_t stream)
{
    const float* emb  = (const float*)d_in[0];
    const int* labels = (const int*)d_in[1];
    const int* depi   = (const int*)d_in[2];
    const int* suii   = (const int*)d_in[3];
    float* out        = (float*)d_out;

    char* ws = (char*)d_ws;
    int*   cnt      = (int*)ws;
    float* d2A      = (float*)(ws + OFF_D2A);
    float* s2B      = (float*)(ws + OFF_S2B);
    float* partials = (float*)(ws + OFF_PART);
    int*   idxA     = (int*)(ws + OFF_IDXA);
    int*   idxB     = (int*)(ws + OFF_IDXB);
    unsigned short* Abf = (unsigned short*)(ws + OFF_BF);
    unsigned short* Bbf = Abf + (size_t)MAXB * DIM;

    const int nrows = in_sizes[0] / DIM;           // 4096

    k_classify<<<1, 1024, 0, stream>>>(labels, depi, suii, cnt, idxA, idxB, nrows);
    const int nblk = (2 * nrows + 3) / 4;          // covers nA+nB waves worst-case
    if (ws_size >= NEED_COMP) {
        k_norms<true><<<nblk, 256, 0, stream>>>(emb, cnt, idxA, idxB, d2A, s2B, Abf, Bbf);
        k_pairs<true><<<NPB, 256, 0, stream>>>(emb, cnt, d2A, s2B, idxA, idxB, Abf, Bbf, partials);
    } else {
        k_norms<false><<<nblk, 256, 0, stream>>>(emb, cnt, idxA, idxB, d2A, s2B, Abf, Bbf);
        k_pairs<false><<<NPB, 256, 0, stream>>>(emb, cnt, d2A, s2B, idxA, idxB, Abf, Bbf, partials);
    }
    k_final<<<1, NPB, 0, stream>>>(partials, cnt, out);
}